// Round 1
// baseline (442.214 us; speedup 1.0000x reference)
//
#include <hip/hip_runtime.h>
#include <math.h>

#define NB 4
#define NPRED 8400
#define NGT 32
#define NCLS 80
#define ROW 85

// ---------- math helpers (mirror reference fp32 op order) ----------

__device__ __forceinline__ float focal_t(float x, float t) {
    // sigmoid_focal for a single logit/target
    float p = 1.f / (1.f + expf(-x));
    float ce = (fmaxf(x, 0.f) + log1pf(expf(-fabsf(x)))) - x * t; // logaddexp(0,x) - x*t
    float pt = p * t + (1.f - p) * (1.f - t);
    float ompt = 1.f - pt;
    float loss = ce * (ompt * ompt);              // (1-p_t)^GAMMA, GAMMA=2
    float at = 0.25f * t + 0.75f * (1.f - t);     // ALPHA=0.25
    return at * loss;
}

__device__ __forceinline__ float ciou_f(float x1, float y1, float x2, float y2,
                                        float x1g, float y1g, float x2g, float y2g,
                                        float atan_p, float atan_g) {
    float w1 = x2 - x1, h1 = y2 - y1;
    float wg = x2g - x1g, hg = y2g - y1g;
    float iw = fmaxf(fminf(x2, x2g) - fmaxf(x1, x1g), 0.f);
    float ih = fmaxf(fminf(y2, y2g) - fmaxf(y1, y1g), 0.f);
    float inter = iw * ih;
    float uni = w1 * h1 + wg * hg - inter;
    float iou = inter / (uni + 1e-7f);
    float cw = fmaxf(x2, x2g) - fminf(x1, x1g);
    float ch = fmaxf(y2, y2g) - fminf(y1, y1g);
    float diag = cw * cw + ch * ch + 1e-7f;
    float dx = (x1 + x2 - x1g - x2g) * 0.5f;
    float dy = (y1 + y2 - y1g - y2g) * 0.5f;
    float rho2 = dx * dx + dy * dy;
    float diou = 1.f - iou + rho2 / diag;
    float dd = atan_g - atan_p;
    const float CV = (float)(4.0 / (M_PI * M_PI));
    float v = CV * (dd * dd);
    float alpha = v / (1.f - iou + v + 1e-7f);
    return diou + alpha * v;
}

// ---------- kernels ----------

__global__ void init_kernel(double* neg_sum) {
    *neg_sum = 0.0;
}

// one thread per (b, n): writes costT[b][m][n] (transposed layout, GT-major rows)
// and accumulates Sum of neg-focal over all (b,n).
__global__ __launch_bounds__(256) void cost_kernel(
        const float* __restrict__ outputs, const float* __restrict__ targets,
        float* __restrict__ costT, double* __restrict__ neg_sum) {
    __shared__ float g_x1[NGT], g_y1[NGT], g_x2[NGT], g_y2[NGT], g_atan[NGT];
    __shared__ int   g_lab[NGT];
    __shared__ double s_neg[256];

    int b = blockIdx.y;
    int tid = threadIdx.x;
    int n = blockIdx.x * blockDim.x + tid;

    if (tid < NGT) {
        const float* gt = targets + (size_t)(b * NGT + tid) * ROW;
        float xc = gt[0], yc = gt[1], w = gt[2], h = gt[3];
        float x1 = xc - w * 0.5f, y1 = yc - h * 0.5f;
        float x2 = xc + w * 0.5f, y2 = yc + h * 0.5f;
        g_x1[tid] = x1; g_y1[tid] = y1; g_x2[tid] = x2; g_y2[tid] = y2;
        float wg = x2 - x1, hg = y2 - y1;     // post-rounding, as reference
        g_atan[tid] = atanf(wg / hg);
        int lab = 0;
        for (int c = 0; c < NCLS; ++c) {
            if (gt[5 + c] > 0.5f) { lab = c; break; }
        }
        g_lab[tid] = lab;
    }
    __syncthreads();

    double my_neg = 0.0;
    if (n < NPRED) {
        const float* pr = outputs + (size_t)(b * NPRED + n) * ROW;
        float xc = pr[0], yc = pr[1], w = pr[2], h = pr[3];
        float x1 = xc - w * 0.5f, y1 = yc - h * 0.5f;
        float x2 = xc + w * 0.5f, y2 = yc + h * 0.5f;
        float w1 = x2 - x1, h1 = y2 - y1;
        float atan_p = atanf(w1 / h1);

        // S0 = sum_c focal(logit_c, 0)
        float S0 = 0.f;
        for (int c = 0; c < NCLS; ++c) {
            S0 += focal_t(pr[5 + c], 0.f);
        }

        // objectness negative term (NEG_W = 1)
        float conf = pr[4];
        my_neg = (double)focal_t(conf, 0.f);

        for (int m = 0; m < NGT; ++m) {
            float cc = ciou_f(x1, y1, x2, y2,
                              g_x1[m], g_y1[m], g_x2[m], g_y2[m],
                              atan_p, g_atan[m]);
            int lab = g_lab[m];
            float xl = pr[5 + lab];
            float clsv = (S0 - focal_t(xl, 0.f) + focal_t(xl, 1.f)) / 80.f;
            costT[(size_t)(b * NGT + m) * NPRED + n] = cc + clsv;
        }
    }

    s_neg[tid] = my_neg;
    __syncthreads();
    for (int s = 128; s > 0; s >>= 1) {
        if (tid < s) s_neg[tid] += s_neg[tid + s];
        __syncthreads();
    }
    if (tid == 0) atomicAdd(neg_sum, s_neg[0]);
}

// Replicates the reference "hungarian"'s EXACT effective semantics
// (its minv1/way1 copies are never written back; way stays 0; delta=inf/NaN):
//   per GT row i in order:
//     j* = argmin over non-poisoned cols of cost[i][j] (tie -> smallest j)
//     if unassigned(j*): assign
//     else: poison j*; scan j ascending: poison assigned cols, give i the
//           first unassigned col.
__global__ __launch_bounds__(256) void hungarian_kernel(
        const float* __restrict__ costT, int* __restrict__ midx) {
    int b = blockIdx.x;
    const float* C = costT + (size_t)b * NGT * NPRED;
    __shared__ unsigned char state[NPRED]; // 0 free, 1 assigned, 2 poisoned(assigned)
    __shared__ float sval[256];
    __shared__ int   sidx[256];
    __shared__ int   s_midx[NGT];
    int tid = threadIdx.x;

    for (int j = tid; j < NPRED; j += 256) state[j] = 0;
    __syncthreads();

    for (int i = 0; i < NGT; ++i) {
        const float* row = C + (size_t)i * NPRED;
        float best = INFINITY;
        int bidx = NPRED;
        for (int j = tid; j < NPRED; j += 256) {
            float v = (state[j] == 2) ? INFINITY : row[j];
            if (v < best) { best = v; bidx = j; }   // j ascends per-thread: first-min kept
        }
        sval[tid] = best; sidx[tid] = bidx;
        __syncthreads();
        for (int s = 128; s > 0; s >>= 1) {
            if (tid < s) {
                float v2 = sval[tid + s]; int i2 = sidx[tid + s];
                if (v2 < sval[tid] || (v2 == sval[tid] && i2 < sidx[tid])) {
                    sval[tid] = v2; sidx[tid] = i2;
                }
            }
            __syncthreads();
        }
        if (tid == 0) {
            int j1 = sidx[0];
            if (state[j1] == 0) {
                state[j1] = 1; s_midx[i] = j1;
            } else {
                state[j1] = 2;  // poison contested column (also excludes it from walk)
                for (int j = 0; j < NPRED; ++j) {
                    if (state[j] == 1) { state[j] = 2; }
                    else if (state[j] == 0) { state[j] = 1; s_midx[i] = j; break; }
                }
            }
        }
        __syncthreads();
    }
    if (tid < NGT) midx[b * NGT + tid] = s_midx[tid];
}

__global__ __launch_bounds__(128) void finalize_kernel(
        const float* __restrict__ outputs, const float* __restrict__ targets,
        const int* __restrict__ midx, const double* __restrict__ neg_sum,
        float* __restrict__ out) {
    __shared__ float s_siou[128], s_cls[128], s_adj[128];
    int t = threadIdx.x;           // 0..127 -> (b, m)
    int b = t >> 5, m = t & 31;

    const float* gt = targets + (size_t)(b * NGT + m) * ROW;
    int j = midx[b * NGT + m];
    const float* pr = outputs + (size_t)(b * NPRED + j) * ROW;

    // pred box
    float xc = pr[0], yc = pr[1], w = pr[2], h = pr[3];
    float x1 = xc - w * 0.5f, y1 = yc - h * 0.5f;
    float x2 = xc + w * 0.5f, y2 = yc + h * 0.5f;
    float atan_p = atanf((x2 - x1) / (y2 - y1));
    // gt box
    float gxc = gt[0], gyc = gt[1], gw = gt[2], gh = gt[3];
    float x1g = gxc - gw * 0.5f, y1g = gyc - gh * 0.5f;
    float x2g = gxc + gw * 0.5f, y2g = gyc + gh * 0.5f;
    float atan_g = atanf((x2g - x1g) / (y2g - y1g));

    s_siou[t] = ciou_f(x1, y1, x2, y2, x1g, y1g, x2g, y2g, atan_p, atan_g);

    float cls_sum = 0.f;
    for (int c = 0; c < NCLS; ++c) {
        cls_sum += focal_t(pr[5 + c], gt[5 + c]);
    }
    s_cls[t] = cls_sum / 80.f;

    float conf = pr[4];
    s_adj[t] = focal_t(conf, 1.f) - focal_t(conf, 0.f); // pos - neg (NEG_W=1)
    __syncthreads();

    if (t == 0) {
        double ssum = 0.0, csum = 0.0, asum = 0.0;
        for (int k = 0; k < 128; ++k) {
            ssum += (double)s_siou[k];
            csum += (double)s_cls[k];
            asum += (double)s_adj[k];
        }
        float siou = (float)(ssum / 128.0);
        float cls  = (float)(csum / 128.0);
        float obj  = (float)((neg_sum[0] + asum) / (double)(NB * NPRED));
        out[0] = 2.0f * siou + 2.0f * obj + 2.0f * cls;
        out[1] = siou;
        out[2] = obj;
        out[3] = cls;
    }
}

// ---------- launch ----------

extern "C" void kernel_launch(void* const* d_in, const int* in_sizes, int n_in,
                              void* d_out, int out_size, void* d_ws, size_t ws_size,
                              hipStream_t stream) {
    const float* outputs = (const float*)d_in[0];
    const float* targets = (const float*)d_in[1];
    float* out = (float*)d_out;

    char* ws = (char*)d_ws;
    double* neg_sum = (double*)ws;              // 8 B
    int* midx = (int*)(ws + 64);                // 4*32*4 = 512 B
    float* costT = (float*)(ws + 1024);         // 4*32*8400*4 = 4,300,800 B

    init_kernel<<<1, 1, 0, stream>>>(neg_sum);

    dim3 grid1((NPRED + 255) / 256, NB);
    cost_kernel<<<grid1, 256, 0, stream>>>(outputs, targets, costT, neg_sum);

    hungarian_kernel<<<NB, 256, 0, stream>>>(costT, midx);

    finalize_kernel<<<1, 128, 0, stream>>>(outputs, targets, midx, neg_sum, out);
}

// Round 2
// 167.885 us; speedup vs baseline: 2.6340x; 2.6340x over previous
//
#include <hip/hip_runtime.h>
#include <math.h>

#define NB 4
#define NPRED 8400
#define NGT 32
#define NCLS 80
#define ROW 85
#define SEG 64
#define NSEG 132   // ceil(8400/64)

// ---------- math helpers (mirror reference fp32 op order) ----------

__device__ __forceinline__ float focal_t(float x, float t) {
    float p = 1.f / (1.f + expf(-x));
    float ce = (fmaxf(x, 0.f) + log1pf(expf(-fabsf(x)))) - x * t; // logaddexp(0,x) - x*t
    float pt = p * t + (1.f - p) * (1.f - t);
    float ompt = 1.f - pt;
    float loss = ce * (ompt * ompt);              // GAMMA=2
    float at = 0.25f * t + 0.75f * (1.f - t);     // ALPHA=0.25
    return at * loss;
}

__device__ __forceinline__ float ciou_f(float x1, float y1, float x2, float y2,
                                        float x1g, float y1g, float x2g, float y2g,
                                        float atan_p, float atan_g) {
    float w1 = x2 - x1, h1 = y2 - y1;
    float wg = x2g - x1g, hg = y2g - y1g;
    float iw = fmaxf(fminf(x2, x2g) - fmaxf(x1, x1g), 0.f);
    float ih = fmaxf(fminf(y2, y2g) - fmaxf(y1, y1g), 0.f);
    float inter = iw * ih;
    float uni = w1 * h1 + wg * hg - inter;
    float iou = inter / (uni + 1e-7f);
    float cw = fmaxf(x2, x2g) - fminf(x1, x1g);
    float ch = fmaxf(y2, y2g) - fminf(y1, y1g);
    float diag = cw * cw + ch * ch + 1e-7f;
    float dx = (x1 + x2 - x1g - x2g) * 0.5f;
    float dy = (y1 + y2 - y1g - y2g) * 0.5f;
    float rho2 = dx * dx + dy * dy;
    float diou = 1.f - iou + rho2 / diag;
    float dd = atan_g - atan_p;
    const float CV = (float)(4.0 / (M_PI * M_PI));
    float v = CV * (dd * dd);
    float alpha = v / (1.f - iou + v + 1e-7f);
    return diou + alpha * v;
}

// ---------- kernels ----------

__global__ void init_kernel(double* neg_sum) {
    *neg_sum = 0.0;
}

// one thread per (b, n): writes costT[b][m][n], per-(row,segment) min tables
// (each 64-lane wave == one 64-column segment; free shuffle reduce), and the
// neg-focal sum over all (b,n).
__global__ __launch_bounds__(256) void cost_kernel(
        const float* __restrict__ outputs, const float* __restrict__ targets,
        float* __restrict__ costT, float* __restrict__ segval,
        int* __restrict__ segidx, double* __restrict__ neg_sum) {
    __shared__ float g_x1[NGT], g_y1[NGT], g_x2[NGT], g_y2[NGT], g_atan[NGT];
    __shared__ int   g_lab[NGT];
    __shared__ double s_neg[256];

    int b = blockIdx.y;
    int tid = threadIdx.x;
    int n = blockIdx.x * blockDim.x + tid;
    bool valid = (n < NPRED);

    if (tid < NGT) {
        const float* gt = targets + (size_t)(b * NGT + tid) * ROW;
        float xc = gt[0], yc = gt[1], w = gt[2], h = gt[3];
        float x1 = xc - w * 0.5f, y1 = yc - h * 0.5f;
        float x2 = xc + w * 0.5f, y2 = yc + h * 0.5f;
        g_x1[tid] = x1; g_y1[tid] = y1; g_x2[tid] = x2; g_y2[tid] = y2;
        float wg = x2 - x1, hg = y2 - y1;
        g_atan[tid] = atanf(wg / hg);
        int lab = 0;
        for (int c = 0; c < NCLS; ++c) {
            if (gt[5 + c] > 0.5f) { lab = c; break; }
        }
        g_lab[tid] = lab;
    }
    __syncthreads();

    float x1 = 0.f, y1 = 0.f, x2 = 0.f, y2 = 0.f, atan_p = 0.f, S0 = 0.f;
    const float* pr = outputs + (size_t)(b * NPRED + (valid ? n : 0)) * ROW;
    double my_neg = 0.0;
    if (valid) {
        float xc = pr[0], yc = pr[1], w = pr[2], h = pr[3];
        x1 = xc - w * 0.5f; y1 = yc - h * 0.5f;
        x2 = xc + w * 0.5f; y2 = yc + h * 0.5f;
        atan_p = atanf((x2 - x1) / (y2 - y1));
        for (int c = 0; c < NCLS; ++c) S0 += focal_t(pr[5 + c], 0.f);
        my_neg = (double)focal_t(pr[4], 0.f);
    }

    int seg = blockIdx.x * 4 + (tid >> 6);  // this wave's segment id

    for (int m = 0; m < NGT; ++m) {
        float cost = INFINITY;
        if (valid) {
            float cc = ciou_f(x1, y1, x2, y2,
                              g_x1[m], g_y1[m], g_x2[m], g_y2[m],
                              atan_p, g_atan[m]);
            int lab = g_lab[m];
            float xl = pr[5 + lab];
            float clsv = (S0 - focal_t(xl, 0.f) + focal_t(xl, 1.f)) / 80.f;
            cost = cc + clsv;
            costT[(size_t)(b * NGT + m) * NPRED + n] = cost;
        }
        // wave-level (min value, lowest column) reduce -> segment min
        float v = cost; int ci = valid ? n : NPRED;
        #pragma unroll
        for (int off = 32; off >= 1; off >>= 1) {
            float ov = __shfl_xor(v, off);
            int oi = __shfl_xor(ci, off);
            if (ov < v || (ov == v && oi < ci)) { v = ov; ci = oi; }
        }
        if ((tid & 63) == 0) {
            segval[(size_t)(b * NGT + m) * NSEG + seg] = v;
            segidx[(size_t)(b * NGT + m) * NSEG + seg] = ci;
        }
    }

    s_neg[tid] = my_neg;
    __syncthreads();
    for (int s = 128; s > 0; s >>= 1) {
        if (tid < s) s_neg[tid] += s_neg[tid + s];
        __syncthreads();
    }
    if (tid == 0) atomicAdd(neg_sum, s_neg[0]);
}

// Same effective semantics as the reference "hungarian" (see round-0 note):
// per GT row in order, (value, lowest-col) argmin over non-poisoned columns;
// on collision poison contested col then walk columns ascending, poisoning
// assigned ones, taking the first free. Argmin now runs over the 132-entry
// per-row segment-min table in LDS; only poison events trigger a 64-column
// segment rescan from global.
__global__ __launch_bounds__(256) void assign_kernel(
        const float* __restrict__ costT, const float* __restrict__ segval,
        const int* __restrict__ segidx, int* __restrict__ midx) {
    int b = blockIdx.x;
    int tid = threadIdx.x;
    __shared__ float sv[NGT * NSEG];
    __shared__ int   si[NGT * NSEG];
    __shared__ unsigned char state[NPRED]; // 0 free, 1 assigned, 2 poisoned
    __shared__ int s_midx[NGT];
    __shared__ int s_win;
    __shared__ int s_plist[64];
    __shared__ int s_pcnt;

    for (int k = tid; k < NGT * NSEG; k += 256) {
        sv[k] = segval[(size_t)b * NGT * NSEG + k];
        si[k] = segidx[(size_t)b * NGT * NSEG + k];
    }
    for (int j = tid; j < NPRED; j += 256) state[j] = 0;
    __syncthreads();

    const float* C = costT + (size_t)b * NGT * NPRED;

    for (int i = 0; i < NGT; ++i) {
        // one-wave argmin over 132 segment minima
        if (tid < 64) {
            float v = INFINITY; int ci = NPRED;
            for (int s = tid; s < NSEG; s += 64) {
                float vv = sv[i * NSEG + s]; int ii = si[i * NSEG + s];
                if (vv < v || (vv == v && ii < ci)) { v = vv; ci = ii; }
            }
            #pragma unroll
            for (int off = 32; off >= 1; off >>= 1) {
                float ov = __shfl_xor(v, off);
                int oi = __shfl_xor(ci, off);
                if (ov < v || (ov == v && oi < ci)) { v = ov; ci = oi; }
            }
            if (tid == 0) s_win = ci;
        }
        __syncthreads();

        if (tid == 0) {
            s_pcnt = 0;
            int j1 = s_win;
            if (state[j1] == 0) {
                state[j1] = 1; s_midx[i] = j1;
            } else {
                state[j1] = 2; s_plist[s_pcnt++] = j1;
                for (int j = 0; ; ++j) {
                    if (state[j] == 1) { state[j] = 2; s_plist[s_pcnt++] = j; }
                    else if (state[j] == 0) { state[j] = 1; s_midx[i] = j; break; }
                }
            }
        }
        __syncthreads();

        int pc = s_pcnt;
        for (int k = 0; k < pc; ++k) {
            int p = s_plist[k];
            int sg = p >> 6;
            int base = sg << 6;
            int r = tid >> 3, g = tid & 7;   // 32 rows x 8 lanes
            float v = INFINITY; int ci = NPRED;
            for (int q = 0; q < 8; ++q) {
                int col = base + g * 8 + q;
                if (col < NPRED && state[col] != 2) {
                    float vv = C[(size_t)r * NPRED + col];
                    if (vv < v) { v = vv; ci = col; }
                }
            }
            #pragma unroll
            for (int off = 4; off >= 1; off >>= 1) {
                float ov = __shfl_down(v, off, 8);
                int oi = __shfl_down(ci, off, 8);
                if (ov < v || (ov == v && oi < ci)) { v = ov; ci = oi; }
            }
            if (g == 0) { sv[r * NSEG + sg] = v; si[r * NSEG + sg] = ci; }
        }
        __syncthreads();
    }
    if (tid < NGT) midx[b * NGT + tid] = s_midx[tid];
}

__global__ __launch_bounds__(128) void finalize_kernel(
        const float* __restrict__ outputs, const float* __restrict__ targets,
        const int* __restrict__ midx, const double* __restrict__ neg_sum,
        float* __restrict__ out) {
    __shared__ float s_siou[128], s_cls[128], s_adj[128];
    int t = threadIdx.x;
    int b = t >> 5, m = t & 31;

    const float* gt = targets + (size_t)(b * NGT + m) * ROW;
    int j = midx[b * NGT + m];
    const float* pr = outputs + (size_t)(b * NPRED + j) * ROW;

    float xc = pr[0], yc = pr[1], w = pr[2], h = pr[3];
    float x1 = xc - w * 0.5f, y1 = yc - h * 0.5f;
    float x2 = xc + w * 0.5f, y2 = yc + h * 0.5f;
    float atan_p = atanf((x2 - x1) / (y2 - y1));
    float gxc = gt[0], gyc = gt[1], gw = gt[2], gh = gt[3];
    float x1g = gxc - gw * 0.5f, y1g = gyc - gh * 0.5f;
    float x2g = gxc + gw * 0.5f, y2g = gyc + gh * 0.5f;
    float atan_g = atanf((x2g - x1g) / (y2g - y1g));

    s_siou[t] = ciou_f(x1, y1, x2, y2, x1g, y1g, x2g, y2g, atan_p, atan_g);

    float cls_sum = 0.f;
    for (int c = 0; c < NCLS; ++c) cls_sum += focal_t(pr[5 + c], gt[5 + c]);
    s_cls[t] = cls_sum / 80.f;

    float conf = pr[4];
    s_adj[t] = focal_t(conf, 1.f) - focal_t(conf, 0.f);
    __syncthreads();

    if (t == 0) {
        double ssum = 0.0, csum = 0.0, asum = 0.0;
        for (int k = 0; k < 128; ++k) {
            ssum += (double)s_siou[k];
            csum += (double)s_cls[k];
            asum += (double)s_adj[k];
        }
        float siou = (float)(ssum / 128.0);
        float cls  = (float)(csum / 128.0);
        float obj  = (float)((neg_sum[0] + asum) / (double)(NB * NPRED));
        out[0] = 2.0f * siou + 2.0f * obj + 2.0f * cls;
        out[1] = siou;
        out[2] = obj;
        out[3] = cls;
    }
}

// ---------- launch ----------

extern "C" void kernel_launch(void* const* d_in, const int* in_sizes, int n_in,
                              void* d_out, int out_size, void* d_ws, size_t ws_size,
                              hipStream_t stream) {
    const float* outputs = (const float*)d_in[0];
    const float* targets = (const float*)d_in[1];
    float* out = (float*)d_out;

    char* ws = (char*)d_ws;
    double* neg_sum = (double*)ws;                    // 8 B
    int* midx = (int*)(ws + 64);                      // 512 B
    float* segval = (float*)(ws + 1024);              // 4*32*132*4 = 67584 B
    int* segidx = (int*)(ws + 1024 + 67584);          // 67584 B
    float* costT = (float*)(ws + 1024 + 2 * 67584);   // 4*32*8400*4 B

    init_kernel<<<1, 1, 0, stream>>>(neg_sum);

    dim3 grid1((NPRED + 255) / 256, NB);
    cost_kernel<<<grid1, 256, 0, stream>>>(outputs, targets, costT, segval, segidx, neg_sum);

    assign_kernel<<<NB, 256, 0, stream>>>(costT, segval, segidx, midx);

    finalize_kernel<<<1, 128, 0, stream>>>(outputs, targets, midx, neg_sum, out);
}